// Round 6
// baseline (307.781 us; speedup 1.0000x reference)
//
#include <hip/hip_runtime.h>

// 2-layer tanh RNN, B=2048, S=512, I=1, H=64, O=1.
// One wave per batch element. Lane i owns hidden unit i. All three weight
// rows live in VGPRs as PACKED F16 PAIRS (192 f16 = 96 VGPRs), consumed by
// v_dot2_f32_f16 (f32 accumulate). amdgpu_waves_per_eu(2,2) grants the
// 128-VGPR bracket (proven in round 3) so the 96 weight regs stay resident —
// launch_bounds(64,4) in round 5 made the RA demote them to per-step L1
// reloads (VGPR_Count=64).
// Software-pipelined: iter k computes h1[k] and h2[k-1]. h passes between
// steps through PING-PONG LDS buffers (read hbuf[(k-1)&1], write hbuf[k&1]);
// h1[k] is stored immediately after its tanh so the 64 dot2 of the h2 path
// hide the LDS store->load latency before the next iteration reads it.
// Single-wave block -> in-order DS, no __syncthreads. asm "memory" clobbers
// pin the LDS read/store ordering against TBAA/LICM.

#define HID 64
#define SEQ 512

typedef _Float16 half2_t __attribute__((ext_vector_type(2)));
typedef _Float16 half8_t __attribute__((ext_vector_type(8)));

__device__ __forceinline__ float tanh_fast(float x) {
    // tanh(x) = 1 - 2/(exp(2x)+1);  exp(2x) = exp2(x * 2*log2(e))
    float e = __builtin_amdgcn_exp2f(x * 2.8853900817779268f);  // v_exp_f32
    return 1.0f - 2.0f * __builtin_amdgcn_rcpf(e + 1.0f);       // v_rcp_f32
}

__device__ __forceinline__ float dot2(half2_t a, half2_t b, float c) {
    return __builtin_amdgcn_fdot2(a, b, c, false);   // v_dot2_f32_f16
}

__device__ __forceinline__ half2_t pr(half8_t v, int t) {  // t compile-time
    half2_t r; r.x = v[2 * t]; r.y = v[2 * t + 1]; return r;
}

__attribute__((amdgpu_waves_per_eu(2, 2)))
__global__ void __launch_bounds__(64)
rnn2_kernel(const float* __restrict__ x,      // [B][SEQ] (I=1)
            const float* __restrict__ W_ih0,  // [HID][1]
            const float* __restrict__ W_hh0,  // [HID][HID]
            const float* __restrict__ b_ih0,  // [HID]
            const float* __restrict__ b_hh0,  // [HID]
            const float* __restrict__ W_ih1,  // [HID][HID]
            const float* __restrict__ W_hh1,  // [HID][HID]
            const float* __restrict__ b_ih1,  // [HID]
            const float* __restrict__ b_hh1,  // [HID]
            const float* __restrict__ fc_W,   // [1][HID]
            const float* __restrict__ fc_b,   // [1]
            float* __restrict__ out)          // [B]
{
    __shared__ __align__(16) float    x_lds[SEQ];
    __shared__ __align__(16) _Float16 hbuf[2][2][HID];   // [pp][h1|h2][unit]

    const int lane = threadIdx.x;   // 0..63 = hidden unit
    const int b    = blockIdx.x;    // batch element

    // --- Weight rows -> packed f16 pairs in registers (96 VGPRs) ---
    half2_t w0h[HID / 2], wi1h[HID / 2], w1h[HID / 2];
#pragma unroll
    for (int j = 0; j < HID; j += 4) {
        const float4 a = *reinterpret_cast<const float4*>(&W_hh0[lane * HID + j]);
        const float4 c = *reinterpret_cast<const float4*>(&W_ih1[lane * HID + j]);
        const float4 d = *reinterpret_cast<const float4*>(&W_hh1[lane * HID + j]);
        w0h [j/2]   = half2_t{(_Float16)a.x, (_Float16)a.y};
        w0h [j/2+1] = half2_t{(_Float16)a.z, (_Float16)a.w};
        wi1h[j/2]   = half2_t{(_Float16)c.x, (_Float16)c.y};
        wi1h[j/2+1] = half2_t{(_Float16)c.z, (_Float16)c.w};
        w1h [j/2]   = half2_t{(_Float16)d.x, (_Float16)d.y};
        w1h [j/2+1] = half2_t{(_Float16)d.z, (_Float16)d.w};
    }
    const float win0  = W_ih0[lane];
    const float bias0 = b_ih0[lane] + b_hh0[lane];
    const float bias1 = b_ih1[lane] + b_hh1[lane];

    // --- Stage x sequence into LDS (coalesced, f32) ---
#pragma unroll
    for (int t = 0; t < SEQ / HID; ++t)
        x_lds[t * HID + lane] = x[(size_t)b * SEQ + t * HID + lane];

    // --- Prologue: hbuf[0] <- { h1[0], h2[-1]=0 } ---
    hbuf[0][1][lane] = (_Float16)0.0f;
    hbuf[0][0][lane] = (_Float16)tanh_fast(fmaf(x_lds[0], win0, bias0));
    asm volatile("" ::: "memory");

    // --- Main loop: iter k computes h1[k] and h2[k-1] ---
#pragma unroll 1
    for (int k = 1; k < SEQ; ++k) {
        const _Float16* rd1 = hbuf[(k - 1) & 1][0];   // h1[k-1]
        const _Float16* rd2 = hbuf[(k - 1) & 1][1];   // h2[k-2]
        _Float16*       wr1 = hbuf[k & 1][0];
        _Float16*       wr2 = hbuf[k & 1][1];

        // ---- h1[k] = tanh(W_hh0 . h1[k-1] + x[k]*win0 + bias0) ----
        float a1a = 0.f, a1b = 0.f;
#pragma unroll
        for (int j = 0; j < 8; ++j) {
            const half8_t c1 = *reinterpret_cast<const half8_t*>(&rd1[8 * j]);
            a1a = dot2(w0h[4*j+0], pr(c1,0), a1a);
            a1b = dot2(w0h[4*j+1], pr(c1,1), a1b);
            a1a = dot2(w0h[4*j+2], pr(c1,2), a1a);
            a1b = dot2(w0h[4*j+3], pr(c1,3), a1b);
        }
        const float h1n = tanh_fast(a1a + a1b + fmaf(x_lds[k], win0, bias0));
        asm volatile("" ::: "memory");
        wr1[lane] = (_Float16)h1n;        // store early; h2 path hides latency
        asm volatile("" ::: "memory");

        // ---- h2[k-1] = tanh(W_ih1 . h1[k-1] + W_hh1 . h2[k-2] + bias1) ----
        float a2a = 0.f, a2b = 0.f;
#pragma unroll
        for (int j = 0; j < 8; ++j) {
            const half8_t c1 = *reinterpret_cast<const half8_t*>(&rd1[8 * j]);
            const half8_t c2 = *reinterpret_cast<const half8_t*>(&rd2[8 * j]);
            a2a = dot2(wi1h[4*j+0], pr(c1,0), a2a);
            a2b = dot2(wi1h[4*j+1], pr(c1,1), a2b);
            a2a = dot2(wi1h[4*j+2], pr(c1,2), a2a);
            a2b = dot2(wi1h[4*j+3], pr(c1,3), a2b);
            a2a = dot2(w1h [4*j+0], pr(c2,0), a2a);
            a2b = dot2(w1h [4*j+1], pr(c2,1), a2b);
            a2a = dot2(w1h [4*j+2], pr(c2,2), a2a);
            a2b = dot2(w1h [4*j+3], pr(c2,3), a2b);
        }
        const float h2n = tanh_fast(a2a + a2b + bias1);
        asm volatile("" ::: "memory");
        wr2[lane] = (_Float16)h2n;        // h2[k-1]
        asm volatile("" ::: "memory");
    }

    // --- Epilogue: h2[SEQ-1] from h1[SEQ-1], h2[SEQ-2] (in hbuf[1]) ---
    {
        const _Float16* rd1 = hbuf[(SEQ - 1) & 1][0];
        const _Float16* rd2 = hbuf[(SEQ - 1) & 1][1];
        float a2a = 0.f, a2b = 0.f;
#pragma unroll
        for (int j = 0; j < 8; ++j) {
            const half8_t c1 = *reinterpret_cast<const half8_t*>(&rd1[8 * j]);
            const half8_t c2 = *reinterpret_cast<const half8_t*>(&rd2[8 * j]);
            a2a = dot2(wi1h[4*j+0], pr(c1,0), a2a);
            a2b = dot2(wi1h[4*j+1], pr(c1,1), a2b);
            a2a = dot2(wi1h[4*j+2], pr(c1,2), a2a);
            a2b = dot2(wi1h[4*j+3], pr(c1,3), a2b);
            a2a = dot2(w1h [4*j+0], pr(c2,0), a2a);
            a2b = dot2(w1h [4*j+1], pr(c2,1), a2b);
            a2a = dot2(w1h [4*j+2], pr(c2,2), a2a);
            a2b = dot2(w1h [4*j+3], pr(c2,3), a2b);
        }
        const float h2last = tanh_fast(a2a + a2b + bias1);

        // --- Final FC: out[b] = sum_i h2last[i] * fc_W[i] + fc_b ---
        float v = h2last * fc_W[lane];
#pragma unroll
        for (int off = 32; off > 0; off >>= 1)
            v += __shfl_xor(v, off, 64);
        if (lane == 0)
            out[b] = v + fc_b[0];
    }
}

extern "C" void kernel_launch(void* const* d_in, const int* in_sizes, int n_in,
                              void* d_out, int out_size, void* d_ws, size_t ws_size,
                              hipStream_t stream) {
    const float* x     = (const float*)d_in[0];
    const float* W_ih0 = (const float*)d_in[1];
    const float* W_hh0 = (const float*)d_in[2];
    const float* b_ih0 = (const float*)d_in[3];
    const float* b_hh0 = (const float*)d_in[4];
    const float* W_ih1 = (const float*)d_in[5];
    const float* W_hh1 = (const float*)d_in[6];
    const float* b_ih1 = (const float*)d_in[7];
    const float* b_hh1 = (const float*)d_in[8];
    const float* fc_W  = (const float*)d_in[9];
    const float* fc_b  = (const float*)d_in[10];

    rnn2_kernel<<<dim3(2048), dim3(64), 0, stream>>>(
        x, W_ih0, W_hh0, b_ih0, b_hh0, W_ih1, W_hh1, b_ih1, b_hh1,
        fc_W, fc_b, (float*)d_out);
}

// Round 7
// 277.175 us; speedup vs baseline: 1.1104x; 1.1104x over previous
//
#include <hip/hip_runtime.h>

// 2-layer tanh RNN, B=2048, S=512, I=1, H=64, O=1.
// One wave per batch element. Lane i owns hidden unit i. All three weight
// rows live in VGPRs as PACKED F16 PAIRS (192 f16 = 96 VGPRs), consumed by
// v_dot2_f32_f16 (f32 accumulate). amdgpu_waves_per_eu(2,2) grants the
// 128-VGPR bracket so weights stay resident (round 6: VGPR_Count=116).
// MERGED inner loop (round 5 structure): c1 (h1[k-1]) and c2 (h2[k-2]) each
// read ONCE per step (16 ds_read_b128 total, the minimum), feeding SIX
// independent dot2 accumulator chains for ILP. Software-pipelined: iter k
// computes h1[k] and h2[k-1]. Single-wave block -> in-order DS, no
// __syncthreads; asm "memory" clobbers pin LDS read/store ordering.

#define HID 64
#define SEQ 512

typedef _Float16 half2_t __attribute__((ext_vector_type(2)));
typedef _Float16 half8_t __attribute__((ext_vector_type(8)));

struct H2x4 { half2_t h[4]; };   // view of one 16-B LDS chunk as 4 half2

__device__ __forceinline__ float tanh_fast(float x) {
    // tanh(x) = 1 - 2/(exp(2x)+1);  exp(2x) = exp2(x * 2*log2(e))
    float e = __builtin_amdgcn_exp2f(x * 2.8853900817779268f);  // v_exp_f32
    return 1.0f - 2.0f * __builtin_amdgcn_rcpf(e + 1.0f);       // v_rcp_f32
}

__device__ __forceinline__ float dot2(half2_t a, half2_t b, float c) {
    return __builtin_amdgcn_fdot2(a, b, c, false);   // v_dot2_f32_f16
}

__attribute__((amdgpu_waves_per_eu(2, 2)))
__global__ void __launch_bounds__(64)
rnn2_kernel(const float* __restrict__ x,      // [B][SEQ] (I=1)
            const float* __restrict__ W_ih0,  // [HID][1]
            const float* __restrict__ W_hh0,  // [HID][HID]
            const float* __restrict__ b_ih0,  // [HID]
            const float* __restrict__ b_hh0,  // [HID]
            const float* __restrict__ W_ih1,  // [HID][HID]
            const float* __restrict__ W_hh1,  // [HID][HID]
            const float* __restrict__ b_ih1,  // [HID]
            const float* __restrict__ b_hh1,  // [HID]
            const float* __restrict__ fc_W,   // [1][HID]
            const float* __restrict__ fc_b,   // [1]
            float* __restrict__ out)          // [B]
{
    __shared__ __align__(16) float    x_lds[SEQ];
    __shared__ __align__(16) _Float16 h1_lds[HID];
    __shared__ __align__(16) _Float16 h2_lds[HID];

    const int lane = threadIdx.x;   // 0..63 = hidden unit
    const int b    = blockIdx.x;    // batch element

    // --- Weight rows -> packed f16 pairs in registers (96 VGPRs) ---
    half2_t w0h[HID / 2], wi1h[HID / 2], w1h[HID / 2];
#pragma unroll
    for (int j = 0; j < HID; j += 4) {
        const float4 a = *reinterpret_cast<const float4*>(&W_hh0[lane * HID + j]);
        const float4 c = *reinterpret_cast<const float4*>(&W_ih1[lane * HID + j]);
        const float4 d = *reinterpret_cast<const float4*>(&W_hh1[lane * HID + j]);
        w0h [j/2]   = half2_t{(_Float16)a.x, (_Float16)a.y};
        w0h [j/2+1] = half2_t{(_Float16)a.z, (_Float16)a.w};
        wi1h[j/2]   = half2_t{(_Float16)c.x, (_Float16)c.y};
        wi1h[j/2+1] = half2_t{(_Float16)c.z, (_Float16)c.w};
        w1h [j/2]   = half2_t{(_Float16)d.x, (_Float16)d.y};
        w1h [j/2+1] = half2_t{(_Float16)d.z, (_Float16)d.w};
    }
    const float win0  = W_ih0[lane];
    const float bias0 = b_ih0[lane] + b_hh0[lane];
    const float bias1 = b_ih1[lane] + b_hh1[lane];

    // --- Stage x sequence into LDS (coalesced, f32) ---
#pragma unroll
    for (int t = 0; t < SEQ / HID; ++t)
        x_lds[t * HID + lane] = x[(size_t)b * SEQ + t * HID + lane];

    // --- Prologue: h2[-1] = 0; h1[0] = tanh(x0*win0 + bias0) ---
    h2_lds[lane] = (_Float16)0.0f;
    h1_lds[lane] = (_Float16)tanh_fast(fmaf(x_lds[0], win0, bias0));
    asm volatile("" ::: "memory");

    // --- Main loop: iter k computes h1[k] and h2[k-1] ---
    // Entering iter k: h1_lds = h1[k-1], h2_lds = h2[k-2].
#pragma unroll 1
    for (int k = 1; k < SEQ; ++k) {
        float a1a = 0.f, a1b = 0.f;   // W_hh0 . h1[k-1]  -> h1[k]
        float a2a = 0.f, a2b = 0.f;   // W_ih1 . h1[k-1]  -> h2[k-1]
        float a3a = 0.f, a3b = 0.f;   // W_hh1 . h2[k-2]  -> h2[k-1]
#pragma unroll
        for (int j = 0; j < 8; ++j) {  // one 16B chunk of each h vector
            const H2x4 c1 = __builtin_bit_cast(H2x4,
                *reinterpret_cast<const half8_t*>(&h1_lds[8 * j]));
            const H2x4 c2 = __builtin_bit_cast(H2x4,
                *reinterpret_cast<const half8_t*>(&h2_lds[8 * j]));
            a1a = dot2(w0h [4*j+0], c1.h[0], a1a);
            a1b = dot2(w0h [4*j+1], c1.h[1], a1b);
            a1a = dot2(w0h [4*j+2], c1.h[2], a1a);
            a1b = dot2(w0h [4*j+3], c1.h[3], a1b);
            a2a = dot2(wi1h[4*j+0], c1.h[0], a2a);
            a2b = dot2(wi1h[4*j+1], c1.h[1], a2b);
            a2a = dot2(wi1h[4*j+2], c1.h[2], a2a);
            a2b = dot2(wi1h[4*j+3], c1.h[3], a2b);
            a3a = dot2(w1h [4*j+0], c2.h[0], a3a);
            a3b = dot2(w1h [4*j+1], c2.h[1], a3b);
            a3a = dot2(w1h [4*j+2], c2.h[2], a3a);
            a3b = dot2(w1h [4*j+3], c2.h[3], a3b);
        }
        const float h1n = tanh_fast(a1a + a1b + fmaf(x_lds[k], win0, bias0));
        const float h2n = tanh_fast(a2a + a2b + a3a + a3b + bias1);
        asm volatile("" ::: "memory");   // reads above stay above the stores
        h1_lds[lane] = (_Float16)h1n;    // h1[k]
        h2_lds[lane] = (_Float16)h2n;    // h2[k-1]
        asm volatile("" ::: "memory");   // next-iter reads stay below stores
    }

    // --- Epilogue: h2[SEQ-1] from h1[SEQ-1] and h2[SEQ-2] ---
    float a2a = 0.f, a2b = 0.f;
#pragma unroll
    for (int j = 0; j < 8; ++j) {
        const H2x4 c1 = __builtin_bit_cast(H2x4,
            *reinterpret_cast<const half8_t*>(&h1_lds[8 * j]));
        const H2x4 c2 = __builtin_bit_cast(H2x4,
            *reinterpret_cast<const half8_t*>(&h2_lds[8 * j]));
        a2a = dot2(wi1h[4*j+0], c1.h[0], a2a);
        a2b = dot2(wi1h[4*j+1], c1.h[1], a2b);
        a2a = dot2(wi1h[4*j+2], c1.h[2], a2a);
        a2b = dot2(wi1h[4*j+3], c1.h[3], a2b);
        a2a = dot2(w1h [4*j+0], c2.h[0], a2a);
        a2b = dot2(w1h [4*j+1], c2.h[1], a2b);
        a2a = dot2(w1h [4*j+2], c2.h[2], a2a);
        a2b = dot2(w1h [4*j+3], c2.h[3], a2b);
    }
    const float h2last = tanh_fast(a2a + a2b + bias1);

    // --- Final FC: out[b] = sum_i h2last[i] * fc_W[i] + fc_b ---
    float v = h2last * fc_W[lane];
#pragma unroll
    for (int off = 32; off > 0; off >>= 1)
        v += __shfl_xor(v, off, 64);
    if (lane == 0)
        out[b] = v + fc_b[0];
}

extern "C" void kernel_launch(void* const* d_in, const int* in_sizes, int n_in,
                              void* d_out, int out_size, void* d_ws, size_t ws_size,
                              hipStream_t stream) {
    const float* x     = (const float*)d_in[0];
    const float* W_ih0 = (const float*)d_in[1];
    const float* W_hh0 = (const float*)d_in[2];
    const float* b_ih0 = (const float*)d_in[3];
    const float* b_hh0 = (const float*)d_in[4];
    const float* W_ih1 = (const float*)d_in[5];
    const float* W_hh1 = (const float*)d_in[6];
    const float* b_ih1 = (const float*)d_in[7];
    const float* b_hh1 = (const float*)d_in[8];
    const float* fc_W  = (const float*)d_in[9];
    const float* fc_b  = (const float*)d_in[10];

    rnn2_kernel<<<dim3(2048), dim3(64), 0, stream>>>(
        x, W_ih0, W_hh0, b_ih0, b_hh0, W_ih1, W_hh1, b_ih1, b_hh1,
        fc_W, fc_b, (float*)d_out);
}